// Round 4
// baseline (286.637 us; speedup 1.0000x reference)
//
#include <hip/hip_runtime.h>
#include <math.h>

#define N_NODES 30000
#define N_EDGES 150000
#define IN_F 16
#define H_F 32
#define C_F 10
// K = IN*H = 512 hidden units in the edge MLP; 513 piecewise-linear intervals.
// Edge-MLP output theta(a) is piecewise-linear in the scalar a = edge_attr[e]:
// theta(a) = a*A_m + B2_m on interval m.  Tables built by prefix-scan; edges
// grouped by m so each table row is read once into LDS.

// ---------------------------------------------------------------------------
// K0: zero the accumulator/counter region (summed | deg | hist | nitems)
// ---------------------------------------------------------------------------
__global__ void k0_zero(float* __restrict__ p, int n) {
    int i = blockIdx.x * blockDim.x + threadIdx.x;
    int stride = gridDim.x * blockDim.x;
    for (; i < n; i += stride) p[i] = 0.0f;
}

// ---------------------------------------------------------------------------
// K1: breakpoints t_k = -b1_k/W1_k, O(n^2) rank sort (no barriers in loop).
// 1 block x 512.  Ties broken by index -> permutation is exact.
// ---------------------------------------------------------------------------
__global__ void k1_rank(const float* __restrict__ W1, const float* __restrict__ b1,
                        float* __restrict__ tsort, int* __restrict__ ksort) {
    __shared__ float st[512];
    int tid = threadIdx.x;
    float w = W1[tid], b = b1[tid];
    float t = (w != 0.0f) ? (-b / w) : 3.0e38f;
    st[tid] = t;
    __syncthreads();
    int rank = 0;
#pragma unroll 8
    for (int j = 0; j < 512; ++j) {
        float tj = st[j];
        rank += (tj < t || (tj == t && j < tid)) ? 1 : 0;
    }
    tsort[rank] = t;
    ksort[rank] = tid;
}

// ---------------------------------------------------------------------------
// KB1: per-edge prep: in-degree histogram, interval m[e] (binary search in
// LDS tsort), interval histogram.
// ---------------------------------------------------------------------------
__global__ void kb1_prep(const int* __restrict__ ei, const float* __restrict__ ea,
                         const float* __restrict__ tsort,
                         int* __restrict__ deg, int* __restrict__ hist,
                         int* __restrict__ me) {
    __shared__ float ts[512];
    for (int i = threadIdx.x; i < 512; i += blockDim.x) ts[i] = tsort[i];
    __syncthreads();
    int e = blockIdx.x * blockDim.x + threadIdx.x;
    if (e >= N_EDGES) return;
    atomicAdd(&deg[ei[N_EDGES + e]], 1);
    float a = ea[e];
    int lo = 0, hi = 512;
    while (lo < hi) {
        int mid = (lo + hi) >> 1;
        if (ts[mid] < a) lo = mid + 1; else hi = mid;
    }
    me[e] = lo;
    atomicAdd(&hist[lo], 1);
}

// ---------------------------------------------------------------------------
// S_SCAN: single block, 1024 threads.
// Phase A: exclusive scan of deg[30000] -> offs/cur (30/thread).
// Phase B: exclusive scan of hist[513] -> moffs/mcur.
// ---------------------------------------------------------------------------
__global__ void s_scan(const int* __restrict__ deg, const int* __restrict__ hist,
                       int* __restrict__ offs, int* __restrict__ cur,
                       int* __restrict__ moffs, int* __restrict__ mcur) {
    __shared__ int part[1024];
    int t = threadIdx.x;
    int base = t * 30;
    int loc[30];
    int s = 0;
#pragma unroll
    for (int i = 0; i < 30; ++i) {
        int idx = base + i;
        int v = (idx < N_NODES) ? deg[idx] : 0;
        loc[i] = v;
        s += v;
    }
    part[t] = s;
    __syncthreads();
    for (int off = 1; off < 1024; off <<= 1) {
        int v = part[t];
        int add = (t >= off) ? part[t - off] : 0;
        __syncthreads();
        part[t] = v + add;
        __syncthreads();
    }
    int run = (t > 0) ? part[t - 1] : 0;
#pragma unroll
    for (int i = 0; i < 30; ++i) {
        int idx = base + i;
        if (idx < N_NODES) { offs[idx] = run; cur[idx] = run; }
        run += loc[i];
    }
    if (t == 1023) offs[N_NODES] = run;
    __syncthreads();
    // phase B: interval bins
    int v = (t < 513) ? hist[t] : 0;
    part[t] = v;
    __syncthreads();
    for (int off = 1; off < 1024; off <<= 1) {
        int x = part[t];
        int add = (t >= off) ? part[t - off] : 0;
        __syncthreads();
        part[t] = x + add;
        __syncthreads();
    }
    if (t < 513) { int ex = part[t] - v; moffs[t] = ex; mcur[t] = ex; }
    if (t == 513) moffs[513] = part[t];  // == total E
}

// ---------------------------------------------------------------------------
// KB3: fill both CSRs: dst-CSR (ssrc) and m-CSR with reordered edge data
// (esd = (src,dst), eam = a) so k3g reads are contiguous.
// ---------------------------------------------------------------------------
__global__ void kb3_fill(const int* __restrict__ ei, const float* __restrict__ ea,
                         const int* __restrict__ me,
                         int* __restrict__ cur, int* __restrict__ mcur,
                         int* __restrict__ ssrc, int2* __restrict__ esd,
                         float* __restrict__ eam) {
    int e = blockIdx.x * blockDim.x + threadIdx.x;
    if (e >= N_EDGES) return;
    int s = ei[e], d = ei[N_EDGES + e];
    int slot = atomicAdd(&cur[d], 1);
    ssrc[slot] = s;
    int ms = atomicAdd(&mcur[me[e]], 1);
    esd[ms] = make_int2(s, d);
    eam[ms] = ea[e];
}

// ---------------------------------------------------------------------------
// KIT: build chunked work items (m, slotStart, cnt<=128). <=1685 items.
// ---------------------------------------------------------------------------
__global__ void kit_items(const int* __restrict__ moffs, int* __restrict__ nitems,
                          int4* __restrict__ items) {
    int t = blockIdx.x * blockDim.x + threadIdx.x;
    if (t >= 513) return;
    int s0 = moffs[t], s1 = moffs[t + 1];
    int cnt = s1 - s0;
    if (cnt <= 0) return;
    int nch = (cnt + 127) >> 7;
    int base = atomicAdd(nitems, nch);
    for (int c = 0; c < nch; ++c) {
        int st = s0 + c * 128;
        items[base + c] = make_int4(t, st, min(128, s1 - st), 0);
    }
}

// ---------------------------------------------------------------------------
// P1: per-chunk partial sums. 32 chunks of 16 ranks. For chunk c, col j:
//   PbA/PbB: masked base-set partials over k in [16c,16c+16) (natural order)
//   SA/SB:   sorted-rank chunk sums (sgn*w, sgn*b weighted W2 rows)
// ---------------------------------------------------------------------------
__global__ void p1_chunks(const float* __restrict__ W1, const float* __restrict__ b1,
                          const float* __restrict__ W2, const int* __restrict__ ksort,
                          float* __restrict__ PbA, float* __restrict__ PbB,
                          float* __restrict__ SA, float* __restrict__ SB) {
    int c = blockIdx.x & 31;
    int jc = blockIdx.x >> 5;
    int j = jc * 256 + threadIdx.x;
    float ba = 0.0f, bb = 0.0f, sa = 0.0f, sb = 0.0f;
#pragma unroll 4
    for (int s = 0; s < 16; ++s) {
        int k = c * 16 + s;
        float w = W1[k], b = b1[k];
        bool act = (w < 0.0f) || (w == 0.0f && b > 0.0f);
        if (act) {
            float w2 = W2[k * 512 + j];
            ba = fmaf(w, w2, ba);
            bb = fmaf(b, w2, bb);
        }
        int kr = ksort[c * 16 + s];
        float wr = W1[kr], br = b1[kr];
        float sgn = (wr > 0.0f) ? 1.0f : ((wr < 0.0f) ? -1.0f : 0.0f);
        float w2r = W2[kr * 512 + j];
        sa = fmaf(sgn * wr, w2r, sa);
        sb = fmaf(sgn * br, w2r, sb);
    }
    PbA[c * 512 + j] = ba; PbB[c * 512 + j] = bb;
    SA[c * 512 + j] = sa;  SB[c * 512 + j] = sb;
}

// ---------------------------------------------------------------------------
// P2: per-column scan over the 32 chunks.
// ---------------------------------------------------------------------------
__global__ void p2_prefix(float* __restrict__ PbA, float* __restrict__ PbB,
                          const float* __restrict__ SA, const float* __restrict__ SB) {
    int j = blockIdx.x * 256 + threadIdx.x;
    float bA = 0.0f, bB = 0.0f;
#pragma unroll
    for (int c = 0; c < 32; ++c) { bA += PbA[c * 512 + j]; bB += PbB[c * 512 + j]; }
    float rA = bA, rB = bB;
#pragma unroll
    for (int c = 0; c < 32; ++c) {
        float sA = SA[c * 512 + j], sB = SB[c * 512 + j];
        PbA[c * 512 + j] = rA;
        PbB[c * 512 + j] = rB;
        rA += sA; rB += sB;
    }
}

// ---------------------------------------------------------------------------
// P3: emit A[513][512], B2[513][512] (b2 folded into B2).
// ---------------------------------------------------------------------------
__global__ void p3_emit(const float* __restrict__ W1, const float* __restrict__ b1,
                        const float* __restrict__ b2, const float* __restrict__ W2,
                        const int* __restrict__ ksort,
                        const float* __restrict__ PA, const float* __restrict__ PB,
                        float* __restrict__ A, float* __restrict__ B2t) {
    int c = blockIdx.x & 31;
    int jc = blockIdx.x >> 5;
    int j = jc * 256 + threadIdx.x;
    float runA = PA[c * 512 + j], runB = PB[c * 512 + j];
    float bb2 = b2[j];
#pragma unroll 4
    for (int s = 0; s < 16; ++s) {
        int m = c * 16 + s;
        A[m * 512 + j]   = runA;
        B2t[m * 512 + j] = runB + bb2;
        int k = ksort[m];
        float w = W1[k], b = b1[k];
        float sgn = (w > 0.0f) ? 1.0f : ((w < 0.0f) ? -1.0f : 0.0f);
        float w2 = W2[k * 512 + j];
        runA = fmaf(sgn * w, w2, runA);
        runB = fmaf(sgn * b, w2, runB);
    }
    if (c == 31) {
        A[512 * 512 + j]   = runA;
        B2t[512 * 512 + j] = runB + bb2;
    }
}

// ---------------------------------------------------------------------------
// K3G: grouped edge message. One work item = one interval chunk (<=128 edges).
// A_m/B2_m rows cached in LDS (bank = lane, conflict-free). 8 edges in
// flight per block (32 lanes each). Atomic scatter to summed[dst].
// ---------------------------------------------------------------------------
__global__ void __launch_bounds__(256) k3g(const float* __restrict__ x,
                                           const int2* __restrict__ esd,
                                           const float* __restrict__ eam,
                                           const float* __restrict__ A,
                                           const float* __restrict__ B2t,
                                           const int4* __restrict__ items,
                                           const int* __restrict__ nitems,
                                           float* __restrict__ summed) {
    __shared__ float sA[512], sB[512];
    int bid = blockIdx.x;
    if (bid >= nitems[0]) return;
    int4 it = items[bid];
    int m = it.x, start = it.y, cnt = it.z;
    const float* Ar = A + m * 512;
    const float* Br = B2t + m * 512;
    for (int i = threadIdx.x; i < 512; i += 256) { sA[i] = Ar[i]; sB[i] = Br[i]; }
    __syncthreads();
    int grp = threadIdx.x >> 5, lane = threadIdx.x & 31;
    for (int c = grp; c < cnt; c += 8) {
        int slot = start + c;
        int2 sd = esd[slot];
        float a = eam[slot];
        float xv = (lane < 16) ? x[sd.x * 16 + lane] : 0.0f;
        float xa = 0.0f, xb = 0.0f;
#pragma unroll
        for (int i = 0; i < 16; ++i) {
            float xi = __shfl(xv, i, 32);
            xa = fmaf(xi, sA[i * 32 + lane], xa);
            xb = fmaf(xi, sB[i * 32 + lane], xb);
        }
        atomicAdd(&summed[sd.y * 32 + lane], fmaf(a, xa, xb));
    }
}

// ---------------------------------------------------------------------------
// K4: per-node: aggr = summed/max(cnt,1); h1 = relu(aggr + x@root + bias1);
// xw = h1@Wg; dinv = rsqrt(indeg + 1). cnt = offs[n+1]-offs[n].
// ---------------------------------------------------------------------------
__global__ void k4_nodes(const float* __restrict__ x, const float* __restrict__ summed,
                         const int* __restrict__ offs,
                         const float* __restrict__ root, const float* __restrict__ bias1,
                         const float* __restrict__ Wg,
                         float* __restrict__ xw, float* __restrict__ dinv) {
    __shared__ float sroot[512], sb1[32], swg[320];
    for (int i = threadIdx.x; i < 512; i += blockDim.x) sroot[i] = root[i];
    for (int i = threadIdx.x; i < 32; i += blockDim.x) sb1[i] = bias1[i];
    for (int i = threadIdx.x; i < 320; i += blockDim.x) swg[i] = Wg[i];
    __syncthreads();
    int n = blockIdx.x * blockDim.x + threadIdx.x;
    if (n >= N_NODES) return;
    float c = (float)(offs[n + 1] - offs[n]);
    float inv = 1.0f / fmaxf(c, 1.0f);
    float xr[16];
#pragma unroll
    for (int i = 0; i < 16; ++i) xr[i] = x[n * 16 + i];
    float acc[10];
#pragma unroll
    for (int cc = 0; cc < 10; ++cc) acc[cc] = 0.0f;
#pragma unroll
    for (int o = 0; o < 32; ++o) {
        float h = summed[n * 32 + o] * inv + sb1[o];
#pragma unroll
        for (int i = 0; i < 16; ++i) h = fmaf(xr[i], sroot[i * 32 + o], h);
        h = fmaxf(h, 0.0f);
#pragma unroll
        for (int cc = 0; cc < 10; ++cc) acc[cc] = fmaf(h, swg[o * 10 + cc], acc[cc]);
    }
#pragma unroll
    for (int cc = 0; cc < 10; ++cc) xw[n * 10 + cc] = acc[cc];
    dinv[n] = rsqrtf(c + 1.0f);
}

// ---------------------------------------------------------------------------
// K56: fused GCN gather + self-loop + bias + log_softmax -> d_out.
// ---------------------------------------------------------------------------
__global__ void k56_final(const int* __restrict__ offs, const int* __restrict__ ssrc,
                          const float* __restrict__ xw, const float* __restrict__ dinv,
                          const float* __restrict__ bg, float* __restrict__ out) {
    __shared__ float sbg[16];
    if (threadIdx.x < 10) sbg[threadIdx.x] = bg[threadIdx.x];
    __syncthreads();
    int n = blockIdx.x * blockDim.x + threadIdx.x;
    if (n >= N_NODES) return;
    float dn = dinv[n];
    float d2 = dn * dn;
    float acc[10];
#pragma unroll
    for (int c = 0; c < 10; ++c) acc[c] = fmaf(xw[n * 10 + c], d2, sbg[c]);
    int s0 = offs[n], s1 = offs[n + 1];
    for (int sl = s0; sl < s1; ++sl) {
        int s = ssrc[sl];
        float nf = dinv[s] * dn;
#pragma unroll
        for (int c = 0; c < 10; ++c) acc[c] = fmaf(xw[s * 10 + c], nf, acc[c]);
    }
    float mx = -1e30f;
#pragma unroll
    for (int c = 0; c < 10; ++c) mx = fmaxf(mx, acc[c]);
    float se = 0.0f;
#pragma unroll
    for (int c = 0; c < 10; ++c) se += expf(acc[c] - mx);
    float lse = logf(se) + mx;
#pragma unroll
    for (int c = 0; c < 10; ++c) out[n * 10 + c] = acc[c] - lse;
}

// ---------------------------------------------------------------------------
extern "C" void kernel_launch(void* const* d_in, const int* in_sizes, int n_in,
                              void* d_out, int out_size, void* d_ws, size_t ws_size,
                              hipStream_t stream) {
    const float* x     = (const float*)d_in[0];
    const float* ea    = (const float*)d_in[1];
    const float* W1    = (const float*)d_in[2];
    const float* b1    = (const float*)d_in[3];
    const float* W2    = (const float*)d_in[4];
    const float* b2    = (const float*)d_in[5];
    const float* root  = (const float*)d_in[6];
    const float* bias1 = (const float*)d_in[7];
    const float* Wg    = (const float*)d_in[8];
    const float* bg    = (const float*)d_in[9];
    const int*   ei    = (const int*)d_in[10];
    float* out = (float*)d_out;

    // workspace layout (4-byte units)
    float* A      = (float*)d_ws;                    // 513*512
    float* B2t    = A + 513 * 512;                   // 513*512
    float* tsort  = B2t + 513 * 512;                 // 512
    int*   ksort  = (int*)(tsort + 512);             // 512
    int4*  items  = (int4*)(ksort + 512);            // 1792 int4 (16B-aligned here)
    float* summed = (float*)((int*)items + 1792 * 4);// N*32   <- zero region start
    int*   deg    = (int*)(summed + N_NODES * 32);   // N
    int*   hist   = deg + N_NODES;                   // 513
    int*   nitems = hist + 513;                      // 1      <- zero region end
    int*   offs   = nitems + 1;                      // N+1
    int*   cur    = offs + N_NODES + 1;              // N
    int*   moffs  = cur + N_NODES;                   // 514
    int*   mcur   = moffs + 514;                     // 513
    int*   me     = mcur + 513;                      // E
    int*   ssrc   = me + N_EDGES;                    // E
    int2*  esd    = (int2*)(ssrc + N_EDGES);         // E int2 (offset even -> 8B ok)
    float* eam    = (float*)(esd + N_EDGES);         // E
    float* xw     = eam + N_EDGES;                   // N*10
    float* dinv   = xw + N_NODES * 10;               // N
    float* PbA    = dinv + N_NODES;                  // 32*512
    float* PbB    = PbA + 32 * 512;
    float* SA     = PbB + 32 * 512;
    float* SB     = SA + 32 * 512;

    k0_zero<<<1024, 256, 0, stream>>>(summed, N_NODES * 32 + N_NODES + 513 + 1);
    k1_rank<<<1, 512, 0, stream>>>(W1, b1, tsort, ksort);
    kb1_prep<<<(N_EDGES + 255) / 256, 256, 0, stream>>>(ei, ea, tsort, deg, hist, me);
    s_scan<<<1, 1024, 0, stream>>>(deg, hist, offs, cur, moffs, mcur);
    kb3_fill<<<(N_EDGES + 255) / 256, 256, 0, stream>>>(ei, ea, me, cur, mcur,
                                                        ssrc, esd, eam);
    kit_items<<<3, 256, 0, stream>>>(moffs, nitems, items);
    p1_chunks<<<64, 256, 0, stream>>>(W1, b1, W2, ksort, PbA, PbB, SA, SB);
    p2_prefix<<<2, 256, 0, stream>>>(PbA, PbB, SA, SB);
    p3_emit<<<64, 256, 0, stream>>>(W1, b1, b2, W2, ksort, PbA, PbB, A, B2t);
    k3g<<<1792, 256, 0, stream>>>(x, esd, eam, A, B2t, items, nitems, summed);
    k4_nodes<<<(N_NODES + 255) / 256, 256, 0, stream>>>(x, summed, offs, root, bias1,
                                                        Wg, xw, dinv);
    k56_final<<<(N_NODES + 255) / 256, 256, 0, stream>>>(offs, ssrc, xw, dinv, bg, out);
}

// Round 5
// 172.010 us; speedup vs baseline: 1.6664x; 1.6664x over previous
//
#include <hip/hip_runtime.h>
#include <math.h>

#define N_NODES 30000
#define N_EDGES 150000
#define IN_F 16
#define H_F 32
#define C_F 10
// K = IN*H = 512 hidden units in the edge MLP; 513 piecewise-linear intervals.
// theta(a) = a*A_m + B2_m on interval m; tables stored TRANSPOSED as
// A_t[m][o][i] (o=0..31, i=0..15) so lane o reads its 16 weights as 4 float4s.

// ---------------------------------------------------------------------------
// K0: zero summed[N*32] + deg[N] (contiguous)
// ---------------------------------------------------------------------------
__global__ void k0_zero(float* __restrict__ p, int n) {
    int i = blockIdx.x * blockDim.x + threadIdx.x;
    int stride = gridDim.x * blockDim.x;
    for (; i < n; i += stride) p[i] = 0.0f;
}

// ---------------------------------------------------------------------------
// K1: breakpoints t_k = -b1_k/W1_k, O(n^2) rank sort (no barriers in loop).
// ---------------------------------------------------------------------------
__global__ void k1_rank(const float* __restrict__ W1, const float* __restrict__ b1,
                        float* __restrict__ tsort, int* __restrict__ ksort) {
    __shared__ float st[512];
    int tid = threadIdx.x;
    float w = W1[tid], b = b1[tid];
    float t = (w != 0.0f) ? (-b / w) : 3.0e38f;
    st[tid] = t;
    __syncthreads();
    int rank = 0;
#pragma unroll 8
    for (int j = 0; j < 512; ++j) {
        float tj = st[j];
        rank += (tj < t || (tj == t && j < tid)) ? 1 : 0;
    }
    tsort[rank] = t;
    ksort[rank] = tid;
}

// ---------------------------------------------------------------------------
// KB1: per-edge prep: in-degree histogram + interval me[e] via binary search.
// ---------------------------------------------------------------------------
__global__ void kb1_prep(const int* __restrict__ ei, const float* __restrict__ ea,
                         const float* __restrict__ tsort,
                         int* __restrict__ deg, int* __restrict__ me) {
    __shared__ float ts[512];
    for (int i = threadIdx.x; i < 512; i += blockDim.x) ts[i] = tsort[i];
    __syncthreads();
    int e = blockIdx.x * blockDim.x + threadIdx.x;
    if (e >= N_EDGES) return;
    atomicAdd(&deg[ei[N_EDGES + e]], 1);
    float a = ea[e];
    int lo = 0, hi = 512;
    while (lo < hi) {
        int mid = (lo + hi) >> 1;
        if (ts[mid] < a) lo = mid + 1; else hi = mid;
    }
    me[e] = lo;
}

// ---------------------------------------------------------------------------
// S_SCAN: single block, 1024 threads: exclusive scan of deg -> offs/cur.
// ---------------------------------------------------------------------------
__global__ void s_scan(const int* __restrict__ deg, int* __restrict__ offs,
                       int* __restrict__ cur) {
    __shared__ int part[1024];
    int t = threadIdx.x;
    int base = t * 30;
    int loc[30];
    int s = 0;
#pragma unroll
    for (int i = 0; i < 30; ++i) {
        int idx = base + i;
        int v = (idx < N_NODES) ? deg[idx] : 0;
        loc[i] = v;
        s += v;
    }
    part[t] = s;
    __syncthreads();
    for (int off = 1; off < 1024; off <<= 1) {
        int v = part[t];
        int add = (t >= off) ? part[t - off] : 0;
        __syncthreads();
        part[t] = v + add;
        __syncthreads();
    }
    int run = (t > 0) ? part[t - 1] : 0;
#pragma unroll
    for (int i = 0; i < 30; ++i) {
        int idx = base + i;
        if (idx < N_NODES) { offs[idx] = run; cur[idx] = run; }
        run += loc[i];
    }
    if (t == 1023) offs[N_NODES] = run;
}

// ---------------------------------------------------------------------------
// KB3: dst-CSR fill (source list only).
// ---------------------------------------------------------------------------
__global__ void kb3_fill(const int* __restrict__ ei, int* __restrict__ cur,
                         int* __restrict__ ssrc) {
    int e = blockIdx.x * blockDim.x + threadIdx.x;
    if (e >= N_EDGES) return;
    int d = ei[N_EDGES + e];
    int slot = atomicAdd(&cur[d], 1);
    ssrc[slot] = ei[e];
}

// ---------------------------------------------------------------------------
// P1: per-chunk partial sums over 32 chunks of 16 ranks (linear j layout).
// ---------------------------------------------------------------------------
__global__ void p1_chunks(const float* __restrict__ W1, const float* __restrict__ b1,
                          const float* __restrict__ W2, const int* __restrict__ ksort,
                          float* __restrict__ PbA, float* __restrict__ PbB,
                          float* __restrict__ SA, float* __restrict__ SB) {
    int c = blockIdx.x & 31;
    int jc = blockIdx.x >> 5;
    int j = jc * 256 + threadIdx.x;
    float ba = 0.0f, bb = 0.0f, sa = 0.0f, sb = 0.0f;
#pragma unroll 4
    for (int s = 0; s < 16; ++s) {
        int k = c * 16 + s;
        float w = W1[k], b = b1[k];
        bool act = (w < 0.0f) || (w == 0.0f && b > 0.0f);
        if (act) {
            float w2 = W2[k * 512 + j];
            ba = fmaf(w, w2, ba);
            bb = fmaf(b, w2, bb);
        }
        int kr = ksort[c * 16 + s];
        float wr = W1[kr], br = b1[kr];
        float sgn = (wr > 0.0f) ? 1.0f : ((wr < 0.0f) ? -1.0f : 0.0f);
        float w2r = W2[kr * 512 + j];
        sa = fmaf(sgn * wr, w2r, sa);
        sb = fmaf(sgn * br, w2r, sb);
    }
    PbA[c * 512 + j] = ba; PbB[c * 512 + j] = bb;
    SA[c * 512 + j] = sa;  SB[c * 512 + j] = sb;
}

// ---------------------------------------------------------------------------
// P3S: fused scan + emit. Block (c, jc): sum all 32 masked-base partials +
// prefix of SA/SB for c'<c, then emit 16 rows with TRANSPOSED writes
// A[m*512 + (j&31)*16 + (j>>5)].  Chunk 31 also emits row 512.
// ---------------------------------------------------------------------------
__global__ void p3s_emit(const float* __restrict__ W1, const float* __restrict__ b1,
                         const float* __restrict__ b2, const float* __restrict__ W2,
                         const int* __restrict__ ksort,
                         const float* __restrict__ PbA, const float* __restrict__ PbB,
                         const float* __restrict__ SA, const float* __restrict__ SB,
                         float* __restrict__ A, float* __restrict__ B2t) {
    int c = blockIdx.x & 31;
    int jc = blockIdx.x >> 5;
    int j = jc * 256 + threadIdx.x;
    float runA = 0.0f, runB = 0.0f;
#pragma unroll
    for (int c2 = 0; c2 < 32; ++c2) {
        runA += PbA[c2 * 512 + j];
        runB += PbB[c2 * 512 + j];
        if (c2 < c) { runA += SA[c2 * 512 + j]; runB += SB[c2 * 512 + j]; }
    }
    float bb2 = b2[j];
    int jt = ((j & 31) << 4) | (j >> 5);   // transposed offset within row
#pragma unroll 4
    for (int s = 0; s < 16; ++s) {
        int m = c * 16 + s;
        A[m * 512 + jt]   = runA;
        B2t[m * 512 + jt] = runB + bb2;
        int k = ksort[m];
        float w = W1[k], b = b1[k];
        float sgn = (w > 0.0f) ? 1.0f : ((w < 0.0f) ? -1.0f : 0.0f);
        float w2 = W2[k * 512 + j];
        runA = fmaf(sgn * w, w2, runA);
        runB = fmaf(sgn * b, w2, runB);
    }
    if (c == 31) {
        A[512 * 512 + jt]   = runA;
        B2t[512 * 512 + jt] = runB + bb2;
    }
}

// ---------------------------------------------------------------------------
// K3: per-edge message, 32 lanes/edge (o = lane). m precomputed (me[e]).
// Lane o reads its 16 A-weights + 16 B-weights as 4+4 float4s (own 64B line).
// msg[o] = a*(x . A_m[:,o]) + (x . B2_m[:,o]); atomic scatter to summed[dst].
// ---------------------------------------------------------------------------
__global__ void __launch_bounds__(256) k3_edges(
        const float* __restrict__ x, const float* __restrict__ ea,
        const int* __restrict__ ei, const int* __restrict__ me,
        const float* __restrict__ A, const float* __restrict__ B2t,
        float* __restrict__ summed) {
    int gid = blockIdx.x * blockDim.x + threadIdx.x;
    int lane = gid & 31;
    int e = gid >> 5;
    if (e >= N_EDGES) return;
    float a = ea[e];
    int s = ei[e], d = ei[N_EDGES + e];
    int m = me[e];
    const float4* Ar = (const float4*)(A   + m * 512 + lane * 16);
    const float4* Br = (const float4*)(B2t + m * 512 + lane * 16);
    float4 a0 = Ar[0], a1 = Ar[1], a2 = Ar[2], a3 = Ar[3];
    float4 b0 = Br[0], b1 = Br[1], b2 = Br[2], b3 = Br[3];
    float xv = (lane < 16) ? x[s * 16 + lane] : 0.0f;
    float xa = 0.0f, xb = 0.0f;
    float xi;
    xi = __shfl(xv,  0, 32); xa = fmaf(xi, a0.x, xa); xb = fmaf(xi, b0.x, xb);
    xi = __shfl(xv,  1, 32); xa = fmaf(xi, a0.y, xa); xb = fmaf(xi, b0.y, xb);
    xi = __shfl(xv,  2, 32); xa = fmaf(xi, a0.z, xa); xb = fmaf(xi, b0.z, xb);
    xi = __shfl(xv,  3, 32); xa = fmaf(xi, a0.w, xa); xb = fmaf(xi, b0.w, xb);
    xi = __shfl(xv,  4, 32); xa = fmaf(xi, a1.x, xa); xb = fmaf(xi, b1.x, xb);
    xi = __shfl(xv,  5, 32); xa = fmaf(xi, a1.y, xa); xb = fmaf(xi, b1.y, xb);
    xi = __shfl(xv,  6, 32); xa = fmaf(xi, a1.z, xa); xb = fmaf(xi, b1.z, xb);
    xi = __shfl(xv,  7, 32); xa = fmaf(xi, a1.w, xa); xb = fmaf(xi, b1.w, xb);
    xi = __shfl(xv,  8, 32); xa = fmaf(xi, a2.x, xa); xb = fmaf(xi, b2.x, xb);
    xi = __shfl(xv,  9, 32); xa = fmaf(xi, a2.y, xa); xb = fmaf(xi, b2.y, xb);
    xi = __shfl(xv, 10, 32); xa = fmaf(xi, a2.z, xa); xb = fmaf(xi, b2.z, xb);
    xi = __shfl(xv, 11, 32); xa = fmaf(xi, a2.w, xa); xb = fmaf(xi, b2.w, xb);
    xi = __shfl(xv, 12, 32); xa = fmaf(xi, a3.x, xa); xb = fmaf(xi, b3.x, xb);
    xi = __shfl(xv, 13, 32); xa = fmaf(xi, a3.y, xa); xb = fmaf(xi, b3.y, xb);
    xi = __shfl(xv, 14, 32); xa = fmaf(xi, a3.z, xa); xb = fmaf(xi, b3.z, xb);
    xi = __shfl(xv, 15, 32); xa = fmaf(xi, a3.w, xa); xb = fmaf(xi, b3.w, xb);
    atomicAdd(&summed[d * 32 + lane], fmaf(a, xa, xb));
}

// ---------------------------------------------------------------------------
// K4: per-node: aggr = summed/max(cnt,1); h1 = relu(aggr + x@root + bias1);
// xw12[n][0..9] = h1@Wg; xw12[n][10] = rsqrt(indeg+1); xw12[n][11] = 0.
// ---------------------------------------------------------------------------
__global__ void k4_nodes(const float* __restrict__ x, const float* __restrict__ summed,
                         const int* __restrict__ offs,
                         const float* __restrict__ root, const float* __restrict__ bias1,
                         const float* __restrict__ Wg,
                         float* __restrict__ xw12) {
    __shared__ float sroot[512], sb1[32], swg[320];
    for (int i = threadIdx.x; i < 512; i += blockDim.x) sroot[i] = root[i];
    for (int i = threadIdx.x; i < 32; i += blockDim.x) sb1[i] = bias1[i];
    for (int i = threadIdx.x; i < 320; i += blockDim.x) swg[i] = Wg[i];
    __syncthreads();
    int n = blockIdx.x * blockDim.x + threadIdx.x;
    if (n >= N_NODES) return;
    float c = (float)(offs[n + 1] - offs[n]);
    float inv = 1.0f / fmaxf(c, 1.0f);
    const float4* xp = (const float4*)(x + n * 16);
    float xr[16];
#pragma unroll
    for (int q = 0; q < 4; ++q) {
        float4 v = xp[q];
        xr[q * 4 + 0] = v.x; xr[q * 4 + 1] = v.y;
        xr[q * 4 + 2] = v.z; xr[q * 4 + 3] = v.w;
    }
    const float4* sp = (const float4*)(summed + n * 32);
    float sm[32];
#pragma unroll
    for (int q = 0; q < 8; ++q) {
        float4 v = sp[q];
        sm[q * 4 + 0] = v.x; sm[q * 4 + 1] = v.y;
        sm[q * 4 + 2] = v.z; sm[q * 4 + 3] = v.w;
    }
    float acc[10];
#pragma unroll
    for (int cc = 0; cc < 10; ++cc) acc[cc] = 0.0f;
#pragma unroll
    for (int o = 0; o < 32; ++o) {
        float h = sm[o] * inv + sb1[o];
#pragma unroll
        for (int i = 0; i < 16; ++i) h = fmaf(xr[i], sroot[i * 32 + o], h);
        h = fmaxf(h, 0.0f);
#pragma unroll
        for (int cc = 0; cc < 10; ++cc) acc[cc] = fmaf(h, swg[o * 10 + cc], acc[cc]);
    }
    float4* op = (float4*)(xw12 + n * 12);
    op[0] = make_float4(acc[0], acc[1], acc[2], acc[3]);
    op[1] = make_float4(acc[4], acc[5], acc[6], acc[7]);
    op[2] = make_float4(acc[8], acc[9], rsqrtf(c + 1.0f), 0.0f);
}

// ---------------------------------------------------------------------------
// K56: fused GCN gather + self-loop + bias + log_softmax -> d_out.
// Per neighbor: 3 float4 loads (xw + dinv packed in slot 10).
// ---------------------------------------------------------------------------
__global__ void k56_final(const int* __restrict__ offs, const int* __restrict__ ssrc,
                          const float* __restrict__ xw12,
                          const float* __restrict__ bg, float* __restrict__ out) {
    __shared__ float sbg[16];
    if (threadIdx.x < 10) sbg[threadIdx.x] = bg[threadIdx.x];
    __syncthreads();
    int n = blockIdx.x * blockDim.x + threadIdx.x;
    if (n >= N_NODES) return;
    const float4* base = (const float4*)xw12;
    float4 r0 = base[n * 3], r1 = base[n * 3 + 1], r2 = base[n * 3 + 2];
    float dn = r2.z;
    float d2 = dn * dn;
    float acc[10];
    acc[0] = fmaf(r0.x, d2, sbg[0]); acc[1] = fmaf(r0.y, d2, sbg[1]);
    acc[2] = fmaf(r0.z, d2, sbg[2]); acc[3] = fmaf(r0.w, d2, sbg[3]);
    acc[4] = fmaf(r1.x, d2, sbg[4]); acc[5] = fmaf(r1.y, d2, sbg[5]);
    acc[6] = fmaf(r1.z, d2, sbg[6]); acc[7] = fmaf(r1.w, d2, sbg[7]);
    acc[8] = fmaf(r2.x, d2, sbg[8]); acc[9] = fmaf(r2.y, d2, sbg[9]);
    int s0 = offs[n], s1 = offs[n + 1];
    for (int sl = s0; sl < s1; ++sl) {
        int s = ssrc[sl];
        float4 q0 = base[s * 3], q1 = base[s * 3 + 1], q2 = base[s * 3 + 2];
        float nf = q2.z * dn;
        acc[0] = fmaf(q0.x, nf, acc[0]); acc[1] = fmaf(q0.y, nf, acc[1]);
        acc[2] = fmaf(q0.z, nf, acc[2]); acc[3] = fmaf(q0.w, nf, acc[3]);
        acc[4] = fmaf(q1.x, nf, acc[4]); acc[5] = fmaf(q1.y, nf, acc[5]);
        acc[6] = fmaf(q1.z, nf, acc[6]); acc[7] = fmaf(q1.w, nf, acc[7]);
        acc[8] = fmaf(q2.x, nf, acc[8]); acc[9] = fmaf(q2.y, nf, acc[9]);
    }
    float mx = -1e30f;
#pragma unroll
    for (int c = 0; c < 10; ++c) mx = fmaxf(mx, acc[c]);
    float se = 0.0f;
#pragma unroll
    for (int c = 0; c < 10; ++c) se += expf(acc[c] - mx);
    float lse = logf(se) + mx;
#pragma unroll
    for (int c = 0; c < 10; ++c) out[n * 10 + c] = acc[c] - lse;
}

// ---------------------------------------------------------------------------
extern "C" void kernel_launch(void* const* d_in, const int* in_sizes, int n_in,
                              void* d_out, int out_size, void* d_ws, size_t ws_size,
                              hipStream_t stream) {
    const float* x     = (const float*)d_in[0];
    const float* ea    = (const float*)d_in[1];
    const float* W1    = (const float*)d_in[2];
    const float* b1    = (const float*)d_in[3];
    const float* W2    = (const float*)d_in[4];
    const float* b2    = (const float*)d_in[5];
    const float* root  = (const float*)d_in[6];
    const float* bias1 = (const float*)d_in[7];
    const float* Wg    = (const float*)d_in[8];
    const float* bg    = (const float*)d_in[9];
    const int*   ei    = (const int*)d_in[10];
    float* out = (float*)d_out;

    // workspace layout (4-byte units); xw12 offset is a multiple of 4 floats
    // (16B) for float4 access — offs padded to N+4 to keep that true.
    float* A      = (float*)d_ws;                    // 513*512
    float* B2t    = A + 513 * 512;                   // 513*512
    float* tsort  = B2t + 513 * 512;                 // 512
    int*   ksort  = (int*)(tsort + 512);             // 512
    float* summed = (float*)(ksort + 512);           // N*32   <- zero start
    int*   deg    = (int*)(summed + N_NODES * 32);   // N      <- zero end
    int*   offs   = deg + N_NODES;                   // N+1 (padded to N+4)
    int*   cur    = offs + N_NODES + 4;              // N
    int*   me     = cur + N_NODES;                   // E
    int*   ssrc   = me + N_EDGES;                    // E
    float* xw12   = (float*)(ssrc + N_EDGES);        // N*12 (16B aligned)
    float* PbA    = xw12 + N_NODES * 12;             // 32*512
    float* PbB    = PbA + 32 * 512;
    float* SA     = PbB + 32 * 512;
    float* SB     = SA + 32 * 512;

    k0_zero<<<1024, 256, 0, stream>>>(summed, N_NODES * 33);
    k1_rank<<<1, 512, 0, stream>>>(W1, b1, tsort, ksort);
    kb1_prep<<<(N_EDGES + 255) / 256, 256, 0, stream>>>(ei, ea, tsort, deg, me);
    s_scan<<<1, 1024, 0, stream>>>(deg, offs, cur);
    kb3_fill<<<(N_EDGES + 255) / 256, 256, 0, stream>>>(ei, cur, ssrc);
    p1_chunks<<<64, 256, 0, stream>>>(W1, b1, W2, ksort, PbA, PbB, SA, SB);
    p3s_emit<<<64, 256, 0, stream>>>(W1, b1, b2, W2, ksort, PbA, PbB, SA, SB, A, B2t);
    k3_edges<<<(N_EDGES * 32 + 255) / 256, 256, 0, stream>>>(x, ea, ei, me, A, B2t,
                                                             summed);
    k4_nodes<<<(N_NODES + 255) / 256, 256, 0, stream>>>(x, summed, offs, root, bias1,
                                                        Wg, xw12);
    k56_final<<<(N_NODES + 255) / 256, 256, 0, stream>>>(offs, ssrc, xw12, bg, out);
}